// Round 1
// baseline (3337.449 us; speedup 1.0000x reference)
//
#include <hip/hip_runtime.h>

#define N_ROWS 100000
#define IN_F   8192
#define OUT_F  128
#define NNZ    2000000

// ---------------------------------------------------------------------------
// k0: transpose weight [OUT_F, IN_F] -> wT [IN_F, OUT_F]  (4 MB, runs once/call)
// classic LDS-tiled transpose, both global sides coalesced
// ---------------------------------------------------------------------------
__global__ void transpose_w(const float* __restrict__ w, float* __restrict__ wT) {
    __shared__ float tile[32][33];                 // +1 pad: no bank conflicts
    int x = blockIdx.x * 32 + threadIdx.x;         // col in w   (IN_F dim)
    int y = blockIdx.y * 32 + threadIdx.y;         // row in w   (OUT_F dim)
    #pragma unroll
    for (int i = 0; i < 32; i += 8)
        tile[threadIdx.y + i][threadIdx.x] = w[(size_t)(y + i) * IN_F + x];
    __syncthreads();
    int tx = blockIdx.y * 32 + threadIdx.x;        // col in wT (OUT_F dim)
    int ty = blockIdx.x * 32 + threadIdx.y;        // row in wT (IN_F dim)
    #pragma unroll
    for (int i = 0; i < 32; i += 8)
        wT[(size_t)(ty + i) * OUT_F + tx] = tile[threadIdx.x][threadIdx.y + i];
}

// ---------------------------------------------------------------------------
// k1: out[r][j] = bias[j]   (must run every call; harness doesn't re-poison)
// float4-vectorized: 3.2M float4 stores
// ---------------------------------------------------------------------------
__global__ void init_out(float4* __restrict__ out4, const float4* __restrict__ bias4) {
    int i = blockIdx.x * blockDim.x + threadIdx.x;
    if (i >= N_ROWS * OUT_F / 4) return;
    out4[i] = bias4[i & 31];                       // 128/4 = 32 float4 per row
}

// ---------------------------------------------------------------------------
// k2: scatter. 32 lanes per nnz; lane L handles out cols [4L, 4L+4).
// weight column read is one coalesced float4 per lane from wT.
// ---------------------------------------------------------------------------
__global__ void scatter(const int* __restrict__ rows, const int* __restrict__ cols,
                        const float* __restrict__ vals, const float* __restrict__ wT,
                        float* __restrict__ out) {
    int t    = blockIdx.x * blockDim.x + threadIdx.x;
    int nz   = t >> 5;
    int lane = t & 31;
    if (nz >= NNZ) return;
    int   r = rows[nz];
    int   c = cols[nz];
    float v = vals[nz];
    const float4 w4 = *reinterpret_cast<const float4*>(wT + (size_t)c * OUT_F + lane * 4);
    float* o = out + (size_t)r * OUT_F + lane * 4;
    atomicAdd(o + 0, v * w4.x);
    atomicAdd(o + 1, v * w4.y);
    atomicAdd(o + 2, v * w4.z);
    atomicAdd(o + 3, v * w4.w);
}

// Fallback (ws too small): strided weight reads, correct but slow.
__global__ void scatter_noT(const int* __restrict__ rows, const int* __restrict__ cols,
                            const float* __restrict__ vals, const float* __restrict__ w,
                            float* __restrict__ out) {
    int t    = blockIdx.x * blockDim.x + threadIdx.x;
    int nz   = t >> 5;
    int lane = t & 31;
    if (nz >= NNZ) return;
    int   r = rows[nz];
    int   c = cols[nz];
    float v = vals[nz];
    float* o = out + (size_t)r * OUT_F + lane * 4;
    #pragma unroll
    for (int k = 0; k < 4; ++k) {
        float wv = w[(size_t)(lane * 4 + k) * IN_F + c];
        atomicAdd(o + k, v * wv);
    }
}

extern "C" void kernel_launch(void* const* d_in, const int* in_sizes, int n_in,
                              void* d_out, int out_size, void* d_ws, size_t ws_size,
                              hipStream_t stream) {
    const int*   rows   = (const int*)d_in[0];
    const int*   cols   = (const int*)d_in[1];
    const float* vals   = (const float*)d_in[2];
    const float* weight = (const float*)d_in[3];
    const float* bias   = (const float*)d_in[4];
    float* out = (float*)d_out;
    float* wT  = (float*)d_ws;

    // init out with bias (every call)
    {
        int n4 = N_ROWS * OUT_F / 4;
        init_out<<<(n4 + 255) / 256, 256, 0, stream>>>(
            (float4*)out, (const float4*)bias);
    }

    const size_t wT_bytes = (size_t)IN_F * OUT_F * sizeof(float);
    if (ws_size >= wT_bytes) {
        dim3 b(32, 8), g(IN_F / 32, OUT_F / 32);
        transpose_w<<<g, b, 0, stream>>>(weight, wT);
        long long total = (long long)NNZ * 32;
        scatter<<<(int)((total + 255) / 256), 256, 0, stream>>>(
            rows, cols, vals, wT, out);
    } else {
        long long total = (long long)NNZ * 32;
        scatter_noT<<<(int)((total + 255) / 256), 256, 0, stream>>>(
            rows, cols, vals, weight, out);
    }
}

// Round 2
// 358.186 us; speedup vs baseline: 9.3176x; 9.3176x over previous
//
#include <hip/hip_runtime.h>

#define N_ROWS 100000
#define IN_F   8192
#define OUT_F  128
#define NNZ    2000000

#define SCAN_B   1024
#define NBLK     ((N_ROWS + SCAN_B - 1) / SCAN_B)   // 98
#define NPAD     (NBLK * SCAN_B)                    // 100352

// ---------------------------------------------------------------------------
// transpose weight [OUT_F, IN_F] -> wT [IN_F, OUT_F]
// ---------------------------------------------------------------------------
__global__ void transpose_w(const float* __restrict__ w, float* __restrict__ wT) {
    __shared__ float tile[32][33];
    int x = blockIdx.x * 32 + threadIdx.x;
    int y = blockIdx.y * 32 + threadIdx.y;
    #pragma unroll
    for (int i = 0; i < 32; i += 8)
        tile[threadIdx.y + i][threadIdx.x] = w[(size_t)(y + i) * IN_F + x];
    __syncthreads();
    int tx = blockIdx.y * 32 + threadIdx.x;
    int ty = blockIdx.x * 32 + threadIdx.y;
    #pragma unroll
    for (int i = 0; i < 32; i += 8)
        wT[(size_t)(ty + i) * OUT_F + tx] = tile[threadIdx.x][threadIdx.y + i];
}

// ---------------------------------------------------------------------------
// zero counts[NPAD] + blockSums[SCAN_B]
// ---------------------------------------------------------------------------
__global__ void zero_counts(int* __restrict__ counts, int* __restrict__ blockSums) {
    int i = blockIdx.x * blockDim.x + threadIdx.x;
    if (i < NPAD) counts[i] = 0;
    if (i < SCAN_B) blockSums[i] = 0;
}

// ---------------------------------------------------------------------------
// histogram of rows
// ---------------------------------------------------------------------------
__global__ void hist(const int* __restrict__ rows, int* __restrict__ counts) {
    int i = blockIdx.x * blockDim.x + threadIdx.x;
    if (i < NNZ) atomicAdd(&counts[rows[i]], 1);
}

// ---------------------------------------------------------------------------
// per-block exclusive scan (Hillis-Steele in LDS), emits block totals
// ---------------------------------------------------------------------------
__global__ void scan_blocks(const int* __restrict__ counts, int* __restrict__ partial,
                            int* __restrict__ blockSums) {
    __shared__ int sh[SCAN_B];
    int tid = threadIdx.x;
    int gid = blockIdx.x * SCAN_B + tid;
    int v = counts[gid];
    sh[tid] = v;
    __syncthreads();
    for (int off = 1; off < SCAN_B; off <<= 1) {
        int t = (tid >= off) ? sh[tid - off] : 0;
        __syncthreads();
        sh[tid] += t;
        __syncthreads();
    }
    partial[gid] = sh[tid] - v;                    // exclusive within block
    if (tid == SCAN_B - 1) blockSums[blockIdx.x] = sh[tid];
}

// ---------------------------------------------------------------------------
// single-block exclusive scan of blockSums (in place); NBLK <= SCAN_B
// ---------------------------------------------------------------------------
__global__ void scan_sums(int* __restrict__ blockSums) {
    __shared__ int sh[SCAN_B];
    int tid = threadIdx.x;
    int v = blockSums[tid];                        // padded region zeroed
    sh[tid] = v;
    __syncthreads();
    for (int off = 1; off < SCAN_B; off <<= 1) {
        int t = (tid >= off) ? sh[tid - off] : 0;
        __syncthreads();
        sh[tid] += t;
        __syncthreads();
    }
    blockSums[tid] = sh[tid] - v;                  // exclusive
}

// ---------------------------------------------------------------------------
// offsets[r] = partial[r] + scannedBlockSums[r/SCAN_B]; cursors = copy
// ---------------------------------------------------------------------------
__global__ void finalize_offsets(const int* __restrict__ partial,
                                 const int* __restrict__ blockSums,
                                 int* __restrict__ offsets, int* __restrict__ cursors) {
    int gid = blockIdx.x * SCAN_B + threadIdx.x;
    if (gid < N_ROWS) {
        int off = partial[gid] + blockSums[gid >> 10];
        offsets[gid] = off;
        cursors[gid] = off;
    }
    if (gid == 0) offsets[N_ROWS] = NNZ;
}

// ---------------------------------------------------------------------------
// scatter (col,val) pairs into row-sorted order
// ---------------------------------------------------------------------------
__global__ void scatter_pairs(const int* __restrict__ rows, const int* __restrict__ cols,
                              const float* __restrict__ vals, int* __restrict__ cursors,
                              int2* __restrict__ pairs) {
    int i = blockIdx.x * blockDim.x + threadIdx.x;
    if (i >= NNZ) return;
    int r = rows[i];
    int p = atomicAdd(&cursors[r], 1);
    pairs[p] = make_int2(cols[i], __float_as_int(vals[i]));
}

// ---------------------------------------------------------------------------
// one wave per row: register-accumulated segment reduction, single store
// lane l owns output cols {2l, 2l+1}
// ---------------------------------------------------------------------------
__global__ void __launch_bounds__(256) reduce_rows(const int2* __restrict__ pairs,
                                                   const float* __restrict__ wT,
                                                   const int* __restrict__ offsets,
                                                   const float* __restrict__ bias,
                                                   float* __restrict__ out) {
    int wid  = (blockIdx.x * blockDim.x + threadIdx.x) >> 6;   // row
    int lane = threadIdx.x & 63;
    if (wid >= N_ROWS) return;
    int start = offsets[wid];
    int end   = offsets[wid + 1];
    float2 acc = *reinterpret_cast<const float2*>(bias + 2 * lane);
    int p = start;
    for (; p + 2 <= end; p += 2) {                 // 2x unroll for ILP
        int2 pa = pairs[p];
        int2 pb = pairs[p + 1];
        float va = __int_as_float(pa.y);
        float vb = __int_as_float(pb.y);
        float2 wa = *reinterpret_cast<const float2*>(wT + (size_t)pa.x * OUT_F + 2 * lane);
        float2 wb = *reinterpret_cast<const float2*>(wT + (size_t)pb.x * OUT_F + 2 * lane);
        acc.x += va * wa.x;
        acc.y += va * wa.y;
        acc.x += vb * wb.x;
        acc.y += vb * wb.y;
    }
    if (p < end) {
        int2 pa = pairs[p];
        float va = __int_as_float(pa.y);
        float2 wa = *reinterpret_cast<const float2*>(wT + (size_t)pa.x * OUT_F + 2 * lane);
        acc.x += va * wa.x;
        acc.y += va * wa.y;
    }
    *reinterpret_cast<float2*>(out + (size_t)wid * OUT_F + 2 * lane) = acc;
}

// ---------------------------------------------------------------------------
// fallback path (ws too small): bias init + atomic scatter (round-1 kernel)
// ---------------------------------------------------------------------------
__global__ void init_out(float4* __restrict__ out4, const float4* __restrict__ bias4) {
    int i = blockIdx.x * blockDim.x + threadIdx.x;
    if (i >= N_ROWS * OUT_F / 4) return;
    out4[i] = bias4[i & 31];
}

__global__ void scatter_noT(const int* __restrict__ rows, const int* __restrict__ cols,
                            const float* __restrict__ vals, const float* __restrict__ w,
                            float* __restrict__ out) {
    int t    = blockIdx.x * blockDim.x + threadIdx.x;
    int nz   = t >> 5;
    int lane = t & 31;
    if (nz >= NNZ) return;
    int   r = rows[nz];
    int   c = cols[nz];
    float v = vals[nz];
    float* o = out + (size_t)r * OUT_F + lane * 4;
    #pragma unroll
    for (int k = 0; k < 4; ++k) {
        float wv = w[(size_t)(lane * 4 + k) * IN_F + c];
        atomicAdd(o + k, v * wv);
    }
}

extern "C" void kernel_launch(void* const* d_in, const int* in_sizes, int n_in,
                              void* d_out, int out_size, void* d_ws, size_t ws_size,
                              hipStream_t stream) {
    const int*   rows   = (const int*)d_in[0];
    const int*   cols   = (const int*)d_in[1];
    const float* vals   = (const float*)d_in[2];
    const float* weight = (const float*)d_in[3];
    const float* bias   = (const float*)d_in[4];
    float* out = (float*)d_out;

    // workspace layout
    char* ws = (char*)d_ws;
    size_t off = 0;
    float* wT       = (float*)(ws + off); off += (size_t)IN_F * OUT_F * sizeof(float); // 4 MB
    int*   counts   = (int*)(ws + off);   off += (size_t)NPAD * 4;
    int*   partial  = (int*)(ws + off);   off += (size_t)NPAD * 4;
    int*   offsets  = (int*)(ws + off);   off += (size_t)(N_ROWS + 2) * 4;
    int*   cursors  = (int*)(ws + off);   off += (size_t)N_ROWS * 4;
    int*   blockSums= (int*)(ws + off);   off += (size_t)SCAN_B * 4;
    off = (off + 7) & ~(size_t)7;
    int2*  pairs    = (int2*)(ws + off);  off += (size_t)NNZ * 8;                      // 16 MB

    if (ws_size >= off) {
        // 0. transpose weight (independent of sort chain)
        {
            dim3 b(32, 8), g(IN_F / 32, OUT_F / 32);
            transpose_w<<<g, b, 0, stream>>>(weight, wT);
        }
        // 1. zero counts
        zero_counts<<<(NPAD + 255) / 256, 256, 0, stream>>>(counts, blockSums);
        // 2. histogram
        hist<<<(NNZ + 255) / 256, 256, 0, stream>>>(rows, counts);
        // 3. scan
        scan_blocks<<<NBLK, SCAN_B, 0, stream>>>(counts, partial, blockSums);
        scan_sums<<<1, SCAN_B, 0, stream>>>(blockSums);
        finalize_offsets<<<NBLK, SCAN_B, 0, stream>>>(partial, blockSums, offsets, cursors);
        // 4. scatter into row-sorted order
        scatter_pairs<<<(NNZ + 255) / 256, 256, 0, stream>>>(rows, cols, vals, cursors, pairs);
        // 5. per-row segment reduction (writes bias + sums, no atomics)
        {
            int waves_per_block = 256 / 64;
            int blocks = (N_ROWS + waves_per_block - 1) / waves_per_block;
            reduce_rows<<<blocks, 256, 0, stream>>>(pairs, wT, offsets, bias, out);
        }
    } else {
        // fallback: correct but atomic-bound
        int n4 = N_ROWS * OUT_F / 4;
        init_out<<<(n4 + 255) / 256, 256, 0, stream>>>((float4*)out, (const float4*)bias);
        long long total = (long long)NNZ * 32;
        scatter_noT<<<(int)((total + 255) / 256), 256, 0, stream>>>(rows, cols, vals, weight, out);
    }
}